// Round 2
// baseline (721.277 us; speedup 1.0000x reference)
//
#include <hip/hip_runtime.h>
#include <hip/hip_bf16.h>
#include <cstdint>
#include <cstddef>

// ---------- types / helpers ----------
typedef __bf16  bf16x8  __attribute__((ext_vector_type(8)));
typedef float   f32x4   __attribute__((ext_vector_type(4)));
typedef ushort  ushort8 __attribute__((ext_vector_type(8)));

#define ASYNC16(gp, lp)                                                        \
  __builtin_amdgcn_global_load_lds(                                            \
      (const __attribute__((address_space(1))) void*)(gp),                     \
      (__attribute__((address_space(3))) void*)(lp), 16, 0, 0)

__device__ __forceinline__ ushort f2bf(float f) {
  __hip_bfloat16 h = __float2bfloat16(f);   // RNE
  ushort u; __builtin_memcpy(&u, &h, 2); return u;
}

#define SINF (-1e30f)

// ---------- weight transpose+convert: Wt[n][k] = bf16(W[k][n]) ----------
__global__ __launch_bounds__(256) void transpose_w(
    const float* __restrict__ W0, const float* __restrict__ W1,
    const float* __restrict__ W2, const float* __restrict__ W3,
    ushort* __restrict__ out) {
  __shared__ float tile[32][33];
  const float* W = blockIdx.z == 0 ? W0 : blockIdx.z == 1 ? W1
                 : blockIdx.z == 2 ? W2 : W3;
  ushort* T = out + (size_t)blockIdx.z * (1024u * 1024u);
  const int n0 = blockIdx.x * 32, k0 = blockIdx.y * 32;
  const int t = threadIdx.x;
  const int r = t >> 3, c = (t & 7) * 4;
  float4 v = *(const float4*)&W[(size_t)(k0 + r) * 1024 + n0 + c];
  tile[r][c + 0] = v.x; tile[r][c + 1] = v.y;
  tile[r][c + 2] = v.z; tile[r][c + 3] = v.w;
  __syncthreads();
  ushort4 o;
  o.x = f2bf(tile[c + 0][r]); o.y = f2bf(tile[c + 1][r]);
  o.z = f2bf(tile[c + 2][r]); o.w = f2bf(tile[c + 3][r]);
  *(ushort4*)&T[(size_t)(n0 + r) * 1024 + k0 + c] = o;
}

// ---------- GEMM  C[M,1024] = (A[M,1024] @ Bt^T + bias) * scale ----------
// Bt is bf16 [N=1024][K=1024]. A is f32 (A_F32) or bf16. C is f32 or bf16.
// m97 structure: 128x128 tile, BK=32, 4 waves of 64x64, 16x16x32 bf16 MFMA.
template <bool A_F32, bool C_F32>
__global__ __launch_bounds__(256) void gemm_bt(
    const void* __restrict__ Ap, const ushort* __restrict__ Bt,
    const float* __restrict__ bias, void* __restrict__ Cp,
    int M, float scale) {
  __shared__ ushort As[128 * 32];
  __shared__ ushort Bs[128 * 32];
  const int tid  = threadIdx.x;
  const int lane = tid & 63, w = tid >> 6;
  const int m15  = lane & 15, q4 = lane >> 4;
  const int wm   = w >> 1,  wn = w & 1;
  const int m0 = blockIdx.x * 128, n0 = blockIdx.y * 128;
  const int sr = lane >> 2;          // staging row within 16-row slab
  const int sc = (lane & 3) * 8;     // staging col (8 bf16 = 16B)
  f32x4 acc[4][4] = {};
  for (int k0 = 0; k0 < 1024; k0 += 32) {
    __syncthreads();
    // --- B staging: async 16B direct-to-LDS ---
    #pragma unroll
    for (int j = 0; j < 2; ++j) {
      int n = w * 2 + j;             // slab id 0..7
      int r = n * 16 + sr;           // tile row 0..127
      ASYNC16(&Bt[(size_t)(n0 + r) * 1024 + k0 + sc], &Bs[n * 512]);
    }
    // --- A staging ---
    if constexpr (A_F32) {
      const float* Af = (const float*)Ap;
      #pragma unroll
      for (int h = 0; h < 2; ++h) {
        int g = tid + h * 256;       // group 0..511
        int row = g >> 2, kg = g & 3;
        int ga = min(m0 + row, M - 1);
        const float* src = &Af[(size_t)ga * 1024 + k0 + kg * 8];
        float4 a0 = *(const float4*)src;
        float4 a1 = *(const float4*)(src + 4);
        ushort8 u = { f2bf(a0.x), f2bf(a0.y), f2bf(a0.z), f2bf(a0.w),
                      f2bf(a1.x), f2bf(a1.y), f2bf(a1.z), f2bf(a1.w) };
        *(ushort8*)&As[row * 32 + kg * 8] = u;
      }
    } else {
      const ushort* Ab = (const ushort*)Ap;
      #pragma unroll
      for (int j = 0; j < 2; ++j) {
        int n = w * 2 + j;
        int r = n * 16 + sr;
        int ga = min(m0 + r, M - 1);
        ASYNC16(&Ab[(size_t)ga * 1024 + k0 + sc], &As[n * 512]);
      }
    }
    __syncthreads();
    bf16x8 af[4], bfr[4];
    #pragma unroll
    for (int i = 0; i < 4; ++i)
      af[i] = *(const bf16x8*)&As[(wm * 64 + i * 16 + m15) * 32 + q4 * 8];
    #pragma unroll
    for (int i = 0; i < 4; ++i)
      bfr[i] = *(const bf16x8*)&Bs[(wn * 64 + i * 16 + m15) * 32 + q4 * 8];
    #pragma unroll
    for (int i = 0; i < 4; ++i)
      #pragma unroll
      for (int j = 0; j < 4; ++j)
        acc[i][j] = __builtin_amdgcn_mfma_f32_16x16x32_bf16(af[i], bfr[j],
                                                            acc[i][j], 0, 0, 0);
  }
  // epilogue: C/D layout col=lane&15, row=(lane>>4)*4+reg
  #pragma unroll
  for (int j = 0; j < 4; ++j) {
    int col = n0 + wn * 64 + j * 16 + m15;
    float bb = bias ? bias[col] : 0.f;
    #pragma unroll
    for (int i = 0; i < 4; ++i) {
      #pragma unroll
      for (int r = 0; r < 4; ++r) {
        int row = m0 + wm * 64 + i * 16 + q4 * 4 + r;
        if (row < M) {
          float v = (acc[i][j][r] + bb) * scale;
          if constexpr (C_F32)
            ((float*)Cp)[(size_t)row * 1024 + col] = v;
          else
            ((ushort*)Cp)[(size_t)row * 1024 + col] = f2bf(v);
        }
      }
    }
  }
}

// ---------- fused attention ----------
// grid (7, 16, 8): 64 Q-rows per block, per (b,h). Writes qk logits (f32) and
// wv = softmax(qk) @ V (bf16, into ws). q/k pre-scaled by Dh^-0.25 at GEMM.
__global__ __launch_bounds__(256) void attn(
    const ushort* __restrict__ q_s, const ushort* __restrict__ k_s,
    const ushort* __restrict__ v_s, float* __restrict__ qk_out,
    ushort* __restrict__ wv) {
  __shared__ ushort Kb[64 * 64];        // K chunk [s][d], no pad (global_load_lds)
  __shared__ ushort Vt[64 * 72];        // V chunk transposed [d][s], pad 72
  __shared__ ushort Pw[4][16 * 72];     // per-wave P tile [t][s], pad 72
  const int tid  = threadIdx.x;
  const int lane = tid & 63, w = tid >> 6;
  const int m15  = lane & 15, q4 = lane >> 4;
  const int h = blockIdx.y, b = blockIdx.z;
  const int t0 = blockIdx.x * 64;
  const int trow = t0 + w * 16;         // this wave's 16-row Q band
  // Q fragments held in registers for the whole block (A-layout: m=lane&15)
  const ushort* qrow = &q_s[(size_t)(b * 448 + trow + m15) * 1024 + h * 64];
  bf16x8 qf0 = *(const bf16x8*)&qrow[q4 * 8];
  bf16x8 qf1 = *(const bf16x8*)&qrow[32 + q4 * 8];
  f32x4 o[4] = {};
  float m_r[4] = {SINF, SINF, SINF, SINF};
  float l_r[4] = {0.f, 0.f, 0.f, 0.f};
  const int vr = tid >> 2;              // V staging: s row 0..63
  const int vc = (tid & 3) * 16;        // V staging: d col base
  const int krb = lane >> 3;            // K staging row-in-slab
  const int kc  = (lane & 7) * 8;       // K staging col
  for (int s0 = 0; s0 < 1500; s0 += 64) {
    __syncthreads();                    // protect Kb/Vt reuse
    // stage K chunk (rows clamped; masked at softmax)
    #pragma unroll
    for (int j = 0; j < 2; ++j) {
      int n = w * 2 + j;
      int sg = min(s0 + n * 8 + krb, 1499);
      ASYNC16(&k_s[(size_t)(b * 1500 + sg) * 1024 + h * 64 + kc], &Kb[n * 512]);
    }
    // stage V transposed (clamped rows harmless: P=0 there)
    {
      int sg = min(s0 + vr, 1499);
      const ushort* vp = &v_s[(size_t)(b * 1500 + sg) * 1024 + h * 64 + vc];
      __align__(16) ushort vbuf[16];
      *(uint4*)&vbuf[0] = *(const uint4*)&vp[0];
      *(uint4*)&vbuf[8] = *(const uint4*)&vp[8];
      #pragma unroll
      for (int j = 0; j < 16; ++j) Vt[(vc + j) * 72 + vr] = vbuf[j];
    }
    __syncthreads();
    // QK^T: 4 s-col tiles x 2 k-steps
    f32x4 lg[4];
    #pragma unroll
    for (int scol = 0; scol < 4; ++scol) {
      f32x4 a = {};
      bf16x8 kf0 = *(const bf16x8*)&Kb[(scol * 16 + m15) * 64 + q4 * 8];
      bf16x8 kf1 = *(const bf16x8*)&Kb[(scol * 16 + m15) * 64 + 32 + q4 * 8];
      a = __builtin_amdgcn_mfma_f32_16x16x32_bf16(qf0, kf0, a, 0, 0, 0);
      a = __builtin_amdgcn_mfma_f32_16x16x32_bf16(qf1, kf1, a, 0, 0, 0);
      lg[scol] = a;
    }
    // chunk row-max (16 lanes sharing q4 hold one row's 16 s-values)
    float mc[4] = {SINF, SINF, SINF, SINF};
    #pragma unroll
    for (int scol = 0; scol < 4; ++scol) {
      bool valid = (s0 + scol * 16 + m15) < 1500;
      #pragma unroll
      for (int r = 0; r < 4; ++r)
        mc[r] = fmaxf(mc[r], valid ? lg[scol][r] : SINF);
    }
    #pragma unroll
    for (int off = 1; off < 16; off <<= 1)
      #pragma unroll
      for (int r = 0; r < 4; ++r)
        mc[r] = fmaxf(mc[r], __shfl_xor(mc[r], off));
    // online-softmax rescale
    #pragma unroll
    for (int r = 0; r < 4; ++r) {
      float mn = fmaxf(m_r[r], mc[r]);
      float alpha = __expf(m_r[r] - mn);   // first chunk: exp(-1e30)=0, no NaN
      l_r[r] *= alpha;
      #pragma unroll
      for (int d = 0; d < 4; ++d) o[d][r] *= alpha;
      m_r[r] = mn;
    }
    // P = exp(l - m), qk logit store (f32), row-sum
    float psum[4] = {0.f, 0.f, 0.f, 0.f};
    #pragma unroll
    for (int scol = 0; scol < 4; ++scol) {
      int sg = s0 + scol * 16 + m15;
      bool valid = sg < 1500;
      #pragma unroll
      for (int r = 0; r < 4; ++r) {
        float lv = lg[scol][r];
        float p = valid ? __expf(lv - m_r[r]) : 0.f;
        psum[r] += p;
        Pw[w][(q4 * 4 + r) * 72 + scol * 16 + m15] = f2bf(p);
        if (valid)
          qk_out[(size_t)((b * 16 + h) * 448 + trow + q4 * 4 + r) * 1500 + sg]
              = lv;
      }
    }
    #pragma unroll
    for (int off = 1; off < 16; off <<= 1)
      #pragma unroll
      for (int r = 0; r < 4; ++r)
        psum[r] += __shfl_xor(psum[r], off);
    #pragma unroll
    for (int r = 0; r < 4; ++r) l_r[r] += psum[r];
    // PV: P (A-layout via same-wave LDS round trip) x V^T (B-layout)
    #pragma unroll
    for (int ks = 0; ks < 2; ++ks) {
      bf16x8 pf = *(const bf16x8*)&Pw[w][m15 * 72 + ks * 32 + q4 * 8];
      #pragma unroll
      for (int d = 0; d < 4; ++d) {
        bf16x8 vf = *(const bf16x8*)&Vt[(d * 16 + m15) * 72 + ks * 32 + q4 * 8];
        o[d] = __builtin_amdgcn_mfma_f32_16x16x32_bf16(pf, vf, o[d], 0, 0, 0);
      }
    }
  }
  // normalize + store wv (bf16 workspace)
  #pragma unroll
  for (int d = 0; d < 4; ++d)
    #pragma unroll
    for (int r = 0; r < 4; ++r) {
      float val = o[d][r] / l_r[r];
      wv[(size_t)(b * 448 + trow + q4 * 4 + r) * 1024 + h * 64 + d * 16 + m15]
          = f2bf(val);
    }
}

// ---------- launch ----------
extern "C" void kernel_launch(void* const* d_in, const int* in_sizes, int n_in,
                              void* d_out, int out_size, void* d_ws,
                              size_t ws_size, hipStream_t stream) {
  const float* x  = (const float*)d_in[0];   // [8,448,1024] f32
  const float* xa = (const float*)d_in[1];   // [8,1500,1024] f32
  const float* Wq = (const float*)d_in[2];
  const float* bq = (const float*)d_in[3];
  const float* Wk = (const float*)d_in[4];
  const float* Wv = (const float*)d_in[5];
  const float* bv = (const float*)d_in[6];
  const float* Wo = (const float*)d_in[7];
  const float* bo = (const float*)d_in[8];
  float* out = (float*)d_out;                        // [8,448,1024] f32
  float* qk  = out + (size_t)8 * 448 * 1024;         // [8,16,448,1500] f32
  char* ws = (char*)d_ws;
  ushort* Wt   = (ushort*)ws;                               // 4x 1M bf16 (8 MB)
  ushort* q_s  = (ushort*)(ws + (size_t)8  * 1024 * 1024);  // 3584x1024 bf16
  ushort* k_s  = (ushort*)(ws + (size_t)16 * 1024 * 1024);  // 12000x1024 bf16
  ushort* v_s  = (ushort*)(ws + (size_t)42 * 1024 * 1024);  // 12000x1024 bf16
  ushort* wv_s = (ushort*)(ws + (size_t)68 * 1024 * 1024);  // 3584x1024 bf16

  transpose_w<<<dim3(32, 32, 4), 256, 0, stream>>>(Wq, Wk, Wv, Wo, Wt);
  const float sc = 0.35355339059327373f;  // 64^-0.25
  gemm_bt<true,  false><<<dim3(28, 8), 256, 0, stream>>>(x,  Wt,                bq,      q_s, 3584,  sc);
  gemm_bt<true,  false><<<dim3(94, 8), 256, 0, stream>>>(xa, Wt + 1u*1048576u,  nullptr, k_s, 12000, sc);
  gemm_bt<true,  false><<<dim3(94, 8), 256, 0, stream>>>(xa, Wt + 2u*1048576u,  bv,      v_s, 12000, 1.0f);
  attn<<<dim3(7, 16, 8), 256, 0, stream>>>(q_s, k_s, v_s, qk, wv_s);
  gemm_bt<false, true ><<<dim3(28, 8), 256, 0, stream>>>(wv_s, Wt + 3u*1048576u, bo,     out, 3584,  1.0f);
}